// Round 10
// baseline (176.080 us; speedup 1.0000x reference)
//
#include <hip/hip_runtime.h>
#include <math.h>

// Problem constants
#define B_DIM 32
#define C_DIM 1024
#define MAP 784
#define NMASK 153
#define NTERM 154          // 153 masks + global-max term
#define NROW 160           // row length (154 terms + 6 zero pads; 640B rows)
#define NBIN 77            // 0=center, 1 + q*19 + (r-1)
#define DUMMY_BIN 77
#define MAX1 28            // slots for each lane's primary bin
#define MAX2 6             // slots for secondary (small) bins on lanes 51..63
#define MPW 8              // maps per wave; 1024 blocks x 4 waves x 8 = 32768

// ---------------------------------------------------------------------------
// Compile-time gather schedule, bank-aware b32 (round-6 verified, unchanged).
// ---------------------------------------------------------------------------
struct Sched {
    unsigned short off1[MAX1][64];  // [slot][lane] byte offset, primary bin
    unsigned short off2[MAX2][64];  // [slot][lane] byte offset, secondary bin
    unsigned char  binA[64];
    unsigned char  binB[64];        // DUMMY_BIN for lanes without a 2nd bin
    bool ok;
};

constexpr Sched build_sched() {
    Sched S{};
    S.ok = true;
    short px[NBIN][40] = {};
    int   n[NBIN] = {};
    for (int i = 0; i < 28; ++i)
        for (int j = 0; j < 28; ++j) {
            int dy = i - 14, dx = j - 14, r2 = dx * dx + dy * dy;
            int p = i * 28 + j;
            if (r2 == 0) { px[0][n[0]++] = (short)p; continue; }
            if (r2 > 361) continue;            // r2>361: in NO mask
            int r = 0; while (r * r < r2) ++r; // ceil(sqrt), 1..19
            const int sx[4] = {1, -1, 1, -1}, sy[4] = {1, 1, -1, -1};
            for (int q = 0; q < 4; ++q)
                if (sx[q] * dx >= 0 && sy[q] * dy >= 0) {
                    int b = 1 + q * 19 + (r - 1);
                    if (n[b] >= 40) { S.ok = false; continue; }
                    px[b][n[b]++] = (short)p;
                }
        }
    int ord[NBIN] = {};
    for (int k = 0; k < NBIN; ++k) ord[k] = k;
    for (int a = 0; a < NBIN; ++a) {
        int best = a;
        for (int c = a + 1; c < NBIN; ++c)
            if (n[ord[c]] > n[ord[best]]) best = c;
        int t = ord[a]; ord[a] = ord[best]; ord[best] = t;
    }
    for (int l = 0; l < 64; ++l) {
        S.binA[l] = (unsigned char)ord[l];
        S.binB[l] = (l >= 51) ? (unsigned char)ord[64 + (l - 51)]
                              : (unsigned char)DUMMY_BIN;
        if (n[ord[l]] > MAX1) S.ok = false;
        if (l >= 51 && n[ord[64 + (l - 51)]] > MAX2) S.ok = false;
    }
    {   // greedy bank-aware placement, primary loop
        bool used[64][40] = {};
        for (int s = 0; s < MAX1; ++s) {
            int bankcnt[32] = {};
            for (int l = 0; l < 64; ++l) {
                int bin = S.binA[l], cnt = n[bin];
                int bestp = 0, bestload = 1 << 30; bool haveUnused = false;
                for (int t = 0; t < cnt; ++t)
                    if (!used[l][t]) {
                        int load = bankcnt[px[bin][t] % 32];
                        if (!haveUnused || load < bestload) { haveUnused = true; bestload = load; bestp = t; }
                    }
                if (!haveUnused)
                    for (int t = 0; t < cnt; ++t) {
                        int load = bankcnt[px[bin][t] % 32];
                        if (load < bestload) { bestload = load; bestp = t; }
                    }
                int p = px[bin][bestp];
                if (haveUnused) used[l][bestp] = true;
                S.off1[s][l] = (unsigned short)(p * 4);
                bankcnt[p % 32]++;
            }
        }
        for (int l = 0; l < 64; ++l)
            for (int t = 0; t < n[S.binA[l]]; ++t)
                if (!used[l][t]) S.ok = false;
    }
    {   // secondary loop
        bool used[64][40] = {};
        for (int s = 0; s < MAX2; ++s) {
            int bankcnt[32] = {};
            for (int l = 0; l < 64; ++l) {
                if (S.binB[l] == DUMMY_BIN) {
                    S.off2[s][l] = (unsigned short)((l % 32) * 4);
                    continue;
                }
                int bin = S.binB[l], cnt = n[bin];
                int bestp = 0, bestload = 1 << 30; bool haveUnused = false;
                for (int t = 0; t < cnt; ++t)
                    if (!used[l][t]) {
                        int load = bankcnt[px[bin][t] % 32];
                        if (!haveUnused || load < bestload) { haveUnused = true; bestload = load; bestp = t; }
                    }
                if (!haveUnused)
                    for (int t = 0; t < cnt; ++t) {
                        int load = bankcnt[px[bin][t] % 32];
                        if (load < bestload) { bestload = load; bestp = t; }
                    }
                int p = px[bin][bestp];
                if (haveUnused) used[l][bestp] = true;
                S.off2[s][l] = (unsigned short)(p * 4);
                bankcnt[p % 32]++;
            }
        }
        for (int l = 0; l < 64; ++l)
            if (S.binB[l] != DUMMY_BIN)
                for (int t = 0; t < n[S.binB[l]]; ++t)
                    if (!used[l][t]) S.ok = false;
    }
    return S;
}

static_assert(build_sched().ok, "schedule overflow / unplaced pixel");
__constant__ Sched d_sched = build_sched();

// sbuf per-map layout: [0..76] bins, [77] dummy, [78..153] circles(q*19+r-1)
__device__ __forceinline__ int term_addr(int k) {
    if (k == 0) return 0;                    // center mask
    if (k >= NMASK) return DUMMY_BIN;        // 153 overridden w/ gmax; >153 -> 0
    int t = k - 1, q = (t >> 1) & 3, rm1 = t >> 3;
    return (t & 1) ? 78 + q * 19 + rm1       // circle
                   : 1 + q * 19 + rm1;       // ring
}

// ---------------- K1: map pairs, 2x ILP on the latency chain ---------------
// 1024 blocks x 256 thr; 4 blocks/CU (= all work) -> VGPRs up to 128 are free.
__global__ __launch_bounds__(256, 4) void cac_k1(const float* __restrict__ x,
                                                 float* __restrict__ vt,
                                                 float* __restrict__ partial) {
    __shared__ __align__(16) float smap[4][2 * MAP];   // 2 maps per wave
    __shared__ float sbuf[4][2][160];                  // bins+circles per map
    __shared__ float ssqred[4][NROW];

    const int wave = threadIdx.x >> 6;
    const int lane = threadIdx.x & 63;
    const int pair0 = blockIdx.x * 32 + wave * MPW;

    // hoisted per-lane constants
    const int linA = lane % 19;                          // segment pos (q0-q2)
    const bool inA = lane < 57, inB = lane < 19;
    const int rbA = 1 + lane;                            // lanes>=57 read q3: harmless
    const int rbB = inB ? 58 + lane : DUMMY_BIN;
    const int a0 = term_addr(lane);
    const int a1 = term_addr(lane + 64);
    const int a2 = term_addr(lane + 128);

    // prefetch chunk 0 (maps 0,1) into registers
    const float4 NEG4 = make_float4(-INFINITY, -INFINITY, -INFINITY, -INFINITY);
    const float4* pA = (const float4*)(x + (size_t)pair0 * MAP);
    const float4* pB = (const float4*)(x + (size_t)(pair0 + 1) * MAP);
    float4 A0 = pA[lane], A1 = pA[64 + lane], A2 = pA[128 + lane], A3 = NEG4;
    float4 B0 = pB[lane], B1 = pB[64 + lane], B2 = pB[128 + lane], B3 = NEG4;
    if (lane < 4) { A3 = pA[192 + lane]; B3 = pB[192 + lane]; }

    float* smA = smap[wave];
    float* smB = smap[wave] + MAP;
    float* sbA = sbuf[wave][0];
    float* sbB = sbuf[wave][1];
    float sq0 = 0.0f, sq1 = 0.0f, sq2 = 0.0f;

    #pragma unroll
    for (int c = 0; c < MPW / 2; ++c) {
        // stage both maps (wave-private LDS, no block barrier)
        ((float4*)smA)[lane] = A0; ((float4*)smA)[64 + lane] = A1;
        ((float4*)smA)[128 + lane] = A2;
        ((float4*)smB)[lane] = B0; ((float4*)smB)[64 + lane] = B1;
        ((float4*)smB)[128 + lane] = B2;
        if (lane < 4) { ((float4*)smA)[192 + lane] = A3;
                        ((float4*)smB)[192 + lane] = B3; }
        float gmaxA = fmaxf(fmaxf(fmaxf(A0.x, A0.y), fmaxf(A0.z, A0.w)),
                            fmaxf(fmaxf(A1.x, A1.y), fmaxf(A1.z, A1.w)));
        gmaxA = fmaxf(gmaxA, fmaxf(fmaxf(A2.x, A2.y), fmaxf(A2.z, A2.w)));
        gmaxA = fmaxf(gmaxA, fmaxf(fmaxf(A3.x, A3.y), fmaxf(A3.z, A3.w)));
        float gmaxB = fmaxf(fmaxf(fmaxf(B0.x, B0.y), fmaxf(B0.z, B0.w)),
                            fmaxf(fmaxf(B1.x, B1.y), fmaxf(B1.z, B1.w)));
        gmaxB = fmaxf(gmaxB, fmaxf(fmaxf(B2.x, B2.y), fmaxf(B2.z, B2.w)));
        gmaxB = fmaxf(gmaxB, fmaxf(fmaxf(B3.x, B3.y), fmaxf(B3.z, B3.w)));

        if (c < MPW / 2 - 1) {   // issue next chunk's loads NOW (~380cyc cover)
            const float4* nA = (const float4*)(x + (size_t)(pair0 + 2 * c + 2) * MAP);
            const float4* nB = (const float4*)(x + (size_t)(pair0 + 2 * c + 3) * MAP);
            A0 = nA[lane]; A1 = nA[64 + lane]; A2 = nA[128 + lane]; A3 = NEG4;
            B0 = nB[lane]; B1 = nB[64 + lane]; B2 = nB[128 + lane]; B3 = NEG4;
            if (lane < 4) { A3 = nA[192 + lane]; B3 = nB[192 + lane]; }
        }
        __builtin_amdgcn_wave_barrier();     // LDS writes before reads

        // bank-scheduled gather, both maps interleaved (2 indep chains)
        const char* baseA = (const char*)smA;
        const char* baseB = (const char*)smB;
        float m1A = 0.0f, m2A = 0.0f, m1B = 0.0f, m2B = 0.0f;
        #pragma unroll
        for (int s = 0; s < MAX1; ++s) {
            unsigned off = d_sched.off1[s][lane];
            m1A = fmaxf(m1A, *(const float*)(baseA + off));
            m1B = fmaxf(m1B, *(const float*)(baseB + off));
        }
        #pragma unroll
        for (int s = 0; s < MAX2; ++s) {
            unsigned off = d_sched.off2[s][lane];
            m2A = fmaxf(m2A, *(const float*)(baseA + off));
            m2B = fmaxf(m2B, *(const float*)(baseB + off));
        }
        sbA[d_sched.binA[lane]] = m1A;
        sbA[d_sched.binB[lane]] = m2A;       // dummy slot absorbs pad lanes
        sbB[d_sched.binA[lane]] = m1B;
        sbB[d_sched.binB[lane]] = m2B;

        #pragma unroll
        for (int off = 32; off; off >>= 1) {
            gmaxA = fmaxf(gmaxA, __shfl_xor(gmaxA, off, 64));
            gmaxB = fmaxf(gmaxB, __shfl_xor(gmaxB, off, 64));
        }
        __builtin_amdgcn_wave_barrier();

        // segmented shuffle prefix-max over rings -> circles (4 indep chains)
        float cvA = sbA[0], cvB = sbB[0];
        float rA1 = fmaxf(sbA[rbA], cvA);    // mapA rings q0-q2
        float rA2 = fmaxf(sbA[rbB], cvA);    // mapA rings q3 (lanes 0..18)
        float rB1 = fmaxf(sbB[rbA], cvB);
        float rB2 = fmaxf(sbB[rbB], cvB);
        #pragma unroll
        for (int s = 1; s <= 16; s <<= 1) {
            float uA1 = __shfl_up(rA1, s, 64), uA2 = __shfl_up(rA2, s, 64);
            float uB1 = __shfl_up(rB1, s, 64), uB2 = __shfl_up(rB2, s, 64);
            if (linA >= s) { rA1 = fmaxf(rA1, uA1); rB1 = fmaxf(rB1, uB1); }
            if (lane >= s) { rA2 = fmaxf(rA2, uA2); rB2 = fmaxf(rB2, uB2); }
        }
        if (inA) { sbA[78 + lane] = rA1; sbB[78 + lane] = rB1; }
        if (inB) { sbA[135 + lane] = rA2; sbB[135 + lane] = rB2; }
        __builtin_amdgcn_wave_barrier();

        // terms (one LDS read each) + coalesced row emit, both maps
        float r0A = sbA[a0], r1A = sbA[a1], r2A = sbA[a2];
        float r0B = sbB[a0], r1B = sbB[a1], r2B = sbB[a2];
        r2A = (lane == 25) ? gmaxA : (lane < 26 ? r2A : 0.0f);  // k=153 / pads
        r2B = (lane == 25) ? gmaxB : (lane < 26 ? r2B : 0.0f);

        float* rowA = vt + (size_t)(pair0 + 2 * c) * NROW;
        float* rowB = rowA + NROW;
        rowA[lane] = r0A;      rowB[lane] = r0B;
        rowA[64 + lane] = r1A; rowB[64 + lane] = r1B;
        if (lane < 32) { rowA[128 + lane] = r2A; rowB[128 + lane] = r2B; }

        sq0 += r0A * r0A + r0B * r0B;
        sq1 += r1A * r1A + r1B * r1B;
        sq2 += r2A * r2A + r2B * r2B;
        __builtin_amdgcn_wave_barrier();     // next chunk's bin writes must not race
    }

    // block-level partial sum of squares (deterministic)
    ssqred[wave][lane]      = sq0;
    ssqred[wave][64 + lane] = sq1;
    if (lane < 32) ssqred[wave][128 + lane] = sq2;
    __syncthreads();
    if (threadIdx.x < NROW) {
        int t = threadIdx.x;
        partial[(size_t)blockIdx.x * NROW + t] =
            ssqred[0][t] + ssqred[1][t] + ssqred[2][t] + ssqred[3][t];
    }
}

// ---------------- K2: fused norm-reduce + dot ------------------------------
// 256 blocks x 256 threads; block handles 128 consecutive pairs (same b).
__global__ __launch_bounds__(256) void cac_k2(const float* __restrict__ vt,
                                              const float* __restrict__ partial,
                                              float* __restrict__ out) {
    __shared__ __align__(16) float sinv[NROW];
    const int b = blockIdx.x >> 3;           // 8 blocks per b

    if (threadIdx.x < NROW) {                // redundant per-b norm reduce (L2)
        int t = threadIdx.x;
        const float* p = partial + (size_t)(b * 32) * NROW + t;
        float s = 0.0f;
        #pragma unroll
        for (int j = 0; j < 32; ++j) s += p[j * NROW];   // coalesced over t
        sinv[t] = (t < NTERM) ? 1.0f / (sqrtf(s) + 1e-6f) : 0.0f;
    }
    __syncthreads();

    const int local = threadIdx.x >> 1;      // 0..127
    const int half  = threadIdx.x & 1;
    const int pair  = blockIdx.x * 128 + local;
    const float4* row = (const float4*)(vt + (size_t)pair * NROW + half * 80);
    const float4* w4  = (const float4*)(sinv + half * 80);
    float acc = 0.0f;
    #pragma unroll
    for (int i = 0; i < 20; ++i) {
        float4 v = row[i], w = w4[i];
        acc += v.x * w.x + v.y * w.y + v.z * w.z + v.w * w.w;
    }
    acc += __shfl_xor(acc, 1, 64);
    if (!half) out[pair] = acc;
}

extern "C" void kernel_launch(void* const* d_in, const int* in_sizes, int n_in,
                              void* d_out, int out_size, void* d_ws, size_t ws_size,
                              hipStream_t stream) {
    const float* x = (const float*)d_in[0];
    float* out = (float*)d_out;

    float* vt      = (float*)d_ws;                           // 32768*160 f32 = 21.0 MB
    float* partial = vt + (size_t)B_DIM * C_DIM * NROW;      //  1024*160 f32 = 640 KB

    cac_k1<<<1024, 256, 0, stream>>>(x, vt, partial);
    cac_k2<<<256, 256, 0, stream>>>(vt, partial, out);
}

// Round 11
// 160.463 us; speedup vs baseline: 1.0973x; 1.0973x over previous
//
#include <hip/hip_runtime.h>
#include <math.h>

// Problem constants
#define B_DIM 32
#define C_DIM 1024
#define MAP 784
#define NMASK 153
#define NTERM 154          // 153 masks + global-max term
#define NROW 160           // row length (154 terms + 6 zero pads; 640B rows)
#define NBIN 77            // 0=center, 1 + q*19 + (r-1)
#define DUMMY_BIN 77
#define MAX1 28            // slots for each lane's primary bin
#define MAX2 6             // slots for secondary (small) bins on lanes 51..63
#define MPW 2              // maps per wave; 4096 blocks x 4 waves x 2 = 32768
#define NBLK 4096          // 8 blocks/CU co-resident -> 32 waves/CU (full TLP)

// ---------------------------------------------------------------------------
// Compile-time gather schedule, bank-aware b32 (round-6 verified, unchanged).
// ---------------------------------------------------------------------------
struct Sched {
    unsigned short off1[MAX1][64];  // [slot][lane] byte offset, primary bin
    unsigned short off2[MAX2][64];  // [slot][lane] byte offset, secondary bin
    unsigned char  binA[64];
    unsigned char  binB[64];        // DUMMY_BIN for lanes without a 2nd bin
    bool ok;
};

constexpr Sched build_sched() {
    Sched S{};
    S.ok = true;
    short px[NBIN][40] = {};
    int   n[NBIN] = {};
    for (int i = 0; i < 28; ++i)
        for (int j = 0; j < 28; ++j) {
            int dy = i - 14, dx = j - 14, r2 = dx * dx + dy * dy;
            int p = i * 28 + j;
            if (r2 == 0) { px[0][n[0]++] = (short)p; continue; }
            if (r2 > 361) continue;            // r2>361: in NO mask
            int r = 0; while (r * r < r2) ++r; // ceil(sqrt), 1..19
            const int sx[4] = {1, -1, 1, -1}, sy[4] = {1, 1, -1, -1};
            for (int q = 0; q < 4; ++q)
                if (sx[q] * dx >= 0 && sy[q] * dy >= 0) {
                    int b = 1 + q * 19 + (r - 1);
                    if (n[b] >= 40) { S.ok = false; continue; }
                    px[b][n[b]++] = (short)p;
                }
        }
    int ord[NBIN] = {};
    for (int k = 0; k < NBIN; ++k) ord[k] = k;
    for (int a = 0; a < NBIN; ++a) {
        int best = a;
        for (int c = a + 1; c < NBIN; ++c)
            if (n[ord[c]] > n[ord[best]]) best = c;
        int t = ord[a]; ord[a] = ord[best]; ord[best] = t;
    }
    for (int l = 0; l < 64; ++l) {
        S.binA[l] = (unsigned char)ord[l];
        S.binB[l] = (l >= 51) ? (unsigned char)ord[64 + (l - 51)]
                              : (unsigned char)DUMMY_BIN;
        if (n[ord[l]] > MAX1) S.ok = false;
        if (l >= 51 && n[ord[64 + (l - 51)]] > MAX2) S.ok = false;
    }
    {   // greedy bank-aware placement, primary loop
        bool used[64][40] = {};
        for (int s = 0; s < MAX1; ++s) {
            int bankcnt[32] = {};
            for (int l = 0; l < 64; ++l) {
                int bin = S.binA[l], cnt = n[bin];
                int bestp = 0, bestload = 1 << 30; bool haveUnused = false;
                for (int t = 0; t < cnt; ++t)
                    if (!used[l][t]) {
                        int load = bankcnt[px[bin][t] % 32];
                        if (!haveUnused || load < bestload) { haveUnused = true; bestload = load; bestp = t; }
                    }
                if (!haveUnused)
                    for (int t = 0; t < cnt; ++t) {
                        int load = bankcnt[px[bin][t] % 32];
                        if (load < bestload) { bestload = load; bestp = t; }
                    }
                int p = px[bin][bestp];
                if (haveUnused) used[l][bestp] = true;
                S.off1[s][l] = (unsigned short)(p * 4);
                bankcnt[p % 32]++;
            }
        }
        for (int l = 0; l < 64; ++l)
            for (int t = 0; t < n[S.binA[l]]; ++t)
                if (!used[l][t]) S.ok = false;
    }
    {   // secondary loop
        bool used[64][40] = {};
        for (int s = 0; s < MAX2; ++s) {
            int bankcnt[32] = {};
            for (int l = 0; l < 64; ++l) {
                if (S.binB[l] == DUMMY_BIN) {
                    S.off2[s][l] = (unsigned short)((l % 32) * 4);
                    continue;
                }
                int bin = S.binB[l], cnt = n[bin];
                int bestp = 0, bestload = 1 << 30; bool haveUnused = false;
                for (int t = 0; t < cnt; ++t)
                    if (!used[l][t]) {
                        int load = bankcnt[px[bin][t] % 32];
                        if (!haveUnused || load < bestload) { haveUnused = true; bestload = load; bestp = t; }
                    }
                if (!haveUnused)
                    for (int t = 0; t < cnt; ++t) {
                        int load = bankcnt[px[bin][t] % 32];
                        if (load < bestload) { bestload = load; bestp = t; }
                    }
                int p = px[bin][bestp];
                if (haveUnused) used[l][bestp] = true;
                S.off2[s][l] = (unsigned short)(p * 4);
                bankcnt[p % 32]++;
            }
        }
        for (int l = 0; l < 64; ++l)
            if (S.binB[l] != DUMMY_BIN)
                for (int t = 0; t < n[S.binB[l]]; ++t)
                    if (!used[l][t]) S.ok = false;
    }
    return S;
}

static_assert(build_sched().ok, "schedule overflow / unplaced pixel");
__constant__ Sched d_sched = build_sched();

// sbuf per-wave layout: [0..76] bins, [77] dummy, [78..153] circles(q*19+r-1)
__device__ __forceinline__ int term_addr(int k) {
    if (k == 0) return 0;                    // center mask
    if (k >= NMASK) return DUMMY_BIN;        // 153 overridden w/ gmax; >153 -> 0
    int t = k - 1, q = (t >> 1) & 3, rm1 = t >> 3;
    return (t & 1) ? 78 + q * 19 + rm1       // circle
                   : 1 + q * 19 + rm1;       // ring
}

// ---------------- K1: round-6 body, full-occupancy TLP shape ---------------
// 4096 blocks x 256 thr; LDS 17.7KB -> 8 blocks/CU -> 32 waves/CU.
__global__ __launch_bounds__(256) void cac_k1(const float* __restrict__ x,
                                              float* __restrict__ vt,
                                              float* __restrict__ partial) {
    __shared__ __align__(16) float smap[4][MAP];
    __shared__ float sbuf[4][160];           // bins + circles per wave
    __shared__ float ssqred[4][NROW];

    const int wave = threadIdx.x >> 6;
    const int lane = threadIdx.x & 63;
    const int pair0 = blockIdx.x * (4 * MPW) + wave * MPW;

    // hoisted per-lane constants
    const int linA = lane % 19;                          // segment pos (q0-q2)
    const bool inA = lane < 57, inB = lane < 19;
    const int rbA = 1 + lane;                            // lanes>=57 read q3: harmless
    const int rbB = inB ? 58 + lane : DUMMY_BIN;
    const int a0 = term_addr(lane);
    const int a1 = term_addr(lane + 64);
    const int a2 = term_addr(lane + 128);

    // prefetch map 0
    const float4 NEG4 = make_float4(-INFINITY, -INFINITY, -INFINITY, -INFINITY);
    const float4* xp4 = (const float4*)(x + (size_t)pair0 * MAP);
    float4 t0 = xp4[lane], t1 = xp4[64 + lane], t2 = xp4[128 + lane];
    float4 t3 = NEG4;
    if (lane < 4) t3 = xp4[192 + lane];

    float* smw = smap[wave];
    float* sbw = sbuf[wave];
    float sq0 = 0.0f, sq1 = 0.0f, sq2 = 0.0f;

    #pragma unroll
    for (int m = 0; m < MPW; ++m) {
        ((float4*)smw)[lane]       = t0;
        ((float4*)smw)[64 + lane]  = t1;
        ((float4*)smw)[128 + lane] = t2;
        if (lane < 4) ((float4*)smw)[192 + lane] = t3;
        float gmax = fmaxf(fmaxf(fmaxf(t0.x, t0.y), fmaxf(t0.z, t0.w)),
                           fmaxf(fmaxf(t1.x, t1.y), fmaxf(t1.z, t1.w)));
        gmax = fmaxf(gmax, fmaxf(fmaxf(t2.x, t2.y), fmaxf(t2.z, t2.w)));
        gmax = fmaxf(gmax, fmaxf(fmaxf(t3.x, t3.y), fmaxf(t3.z, t3.w)));

        if (m < MPW - 1) {   // software-pipeline next map's global loads
            const float4* np4 = (const float4*)(x + (size_t)(pair0 + m + 1) * MAP);
            t0 = np4[lane]; t1 = np4[64 + lane]; t2 = np4[128 + lane];
            t3 = NEG4;
            if (lane < 4) t3 = np4[192 + lane];
        }
        __builtin_amdgcn_wave_barrier();     // keep LDS writes before reads

        // bank-scheduled gather (init 0 == masked-max clamp)
        const char* base = (const char*)smw;
        float m1 = 0.0f, m2v = 0.0f;
        #pragma unroll
        for (int s = 0; s < MAX1; ++s)
            m1 = fmaxf(m1, *(const float*)(base + d_sched.off1[s][lane]));
        #pragma unroll
        for (int s = 0; s < MAX2; ++s)
            m2v = fmaxf(m2v, *(const float*)(base + d_sched.off2[s][lane]));
        sbw[d_sched.binA[lane]] = m1;
        sbw[d_sched.binB[lane]] = m2v;       // dummy slot absorbs pad lanes

        #pragma unroll
        for (int off = 32; off; off >>= 1)
            gmax = fmaxf(gmax, __shfl_xor(gmax, off, 64));
        __builtin_amdgcn_wave_barrier();

        // segmented shuffle prefix-max over rings -> circles
        float cval = sbw[0];
        float rA = fmaxf(sbw[rbA], cval);    // rings: q=lane/19, r=lane%19+1
        float rB = fmaxf(sbw[rbB], cval);    // q3 rings on lanes 0..18
        #pragma unroll
        for (int s = 1; s <= 16; s <<= 1) {
            float uA = __shfl_up(rA, s, 64);
            float uB = __shfl_up(rB, s, 64);
            if (linA >= s) rA = fmaxf(rA, uA);
            if (lane >= s) rB = fmaxf(rB, uB);
        }
        if (inA) sbw[78 + lane] = rA;
        if (inB) sbw[135 + lane] = rB;
        __builtin_amdgcn_wave_barrier();

        // terms from one LDS read each; coalesced 640B row emit
        float r0 = sbw[a0];
        float r1 = sbw[a1];
        float r2 = sbw[a2];
        r2 = (lane == 25) ? gmax : (lane < 26 ? r2 : 0.0f);  // k=153 / pads

        float* rowp = vt + (size_t)(pair0 + m) * NROW;
        rowp[lane]      = r0;
        rowp[64 + lane] = r1;
        if (lane < 32) rowp[128 + lane] = r2;
        sq0 += r0 * r0; sq1 += r1 * r1; sq2 += r2 * r2;
        __builtin_amdgcn_wave_barrier();     // next map's bin writes must not race
    }

    // block-level partial sum of squares (deterministic)
    ssqred[wave][lane]      = sq0;
    ssqred[wave][64 + lane] = sq1;
    if (lane < 32) ssqred[wave][128 + lane] = sq2;
    __syncthreads();
    if (threadIdx.x < NROW) {
        int t = threadIdx.x;
        partial[(size_t)blockIdx.x * NROW + t] =
            ssqred[0][t] + ssqred[1][t] + ssqred[2][t] + ssqred[3][t];
    }
}

// ---------------- K2: fused norm-reduce + dot ------------------------------
// 256 blocks x 256 threads; block handles 128 consecutive pairs (same b).
__global__ __launch_bounds__(256) void cac_k2(const float* __restrict__ vt,
                                              const float* __restrict__ partial,
                                              float* __restrict__ out) {
    __shared__ __align__(16) float sinv[NROW];
    const int b = blockIdx.x >> 3;           // 8 blocks per b

    if (threadIdx.x < NROW) {                // redundant per-b norm reduce (L2)
        int t = threadIdx.x;
        const float* p = partial + (size_t)(b * 128) * NROW + t;  // 128 blocks/b
        float s = 0.0f;
        #pragma unroll 8
        for (int j = 0; j < 128; ++j) s += p[(size_t)j * NROW];   // coalesced over t
        sinv[t] = (t < NTERM) ? 1.0f / (sqrtf(s) + 1e-6f) : 0.0f;
    }
    __syncthreads();

    const int local = threadIdx.x >> 1;      // 0..127
    const int half  = threadIdx.x & 1;
    const int pair  = blockIdx.x * 128 + local;
    const float4* row = (const float4*)(vt + (size_t)pair * NROW + half * 80);
    const float4* w4  = (const float4*)(sinv + half * 80);
    float acc = 0.0f;
    #pragma unroll
    for (int i = 0; i < 20; ++i) {
        float4 v = row[i], w = w4[i];
        acc += v.x * w.x + v.y * w.y + v.z * w.z + v.w * w.w;
    }
    acc += __shfl_xor(acc, 1, 64);
    if (!half) out[pair] = acc;
}

extern "C" void kernel_launch(void* const* d_in, const int* in_sizes, int n_in,
                              void* d_out, int out_size, void* d_ws, size_t ws_size,
                              hipStream_t stream) {
    const float* x = (const float*)d_in[0];
    float* out = (float*)d_out;

    float* vt      = (float*)d_ws;                           // 32768*160 f32 = 21.0 MB
    float* partial = vt + (size_t)B_DIM * C_DIM * NROW;      //  4096*160 f32 = 2.6 MB

    cac_k1<<<NBLK, 256, 0, stream>>>(x, vt, partial);
    cac_k2<<<256, 256, 0, stream>>>(vt, partial, out);
}